// Round 3
// baseline (903.203 us; speedup 1.0000x reference)
//
#include <hip/hip_runtime.h>
#include <math.h>

#define F_IN 256
#define CH   16
#define NL   7
#define BN   128            // nodes per bucket (localDst fits 7 bits)
#define MAXB 1024           // max buckets (N <= 131072; src fits 17 bits -> packed int OK)
#define PCHUNK 16384        // edges per placement block (-> ~16-edge runs per bucket = 64B lines)

__device__ __forceinline__ void lds_fadd(float* p, float v) {
    __hip_atomic_fetch_add(p, v, __ATOMIC_RELAXED, __HIP_MEMORY_SCOPE_WORKGROUP);
}

// ---------------------------------------------------------------- count edges per bucket
__global__ __launch_bounds__(256) void k_count(const int* __restrict__ dst, int E,
                                               int* __restrict__ bucketCount) {
    __shared__ int hist[MAXB];
    int t = threadIdx.x;
    for (int i = t; i < MAXB; i += 256) hist[i] = 0;
    __syncthreads();
    for (int e = blockIdx.x * 256 + t; e < E; e += gridDim.x * 256)
        atomicAdd(&hist[dst[e] >> 7], 1);
    __syncthreads();
    for (int b = t; b < MAXB; b += 256)
        if (hist[b]) atomicAdd(&bucketCount[b], hist[b]);
}

// ---------------------------------------------------------------- exclusive scan (1 block, 1024 thr)
__global__ __launch_bounds__(MAXB) void k_scan(const int* __restrict__ bucketCount,
                                               int* __restrict__ bucketStart,
                                               int* __restrict__ cursor) {
    __shared__ int s[MAXB];
    int t = threadIdx.x;
    int v0 = bucketCount[t];
    s[t] = v0;
    __syncthreads();
    for (int d = 1; d < MAXB; d <<= 1) {
        int v = (t >= d) ? s[t - d] : 0;
        __syncthreads();
        s[t] += v;
        __syncthreads();
    }
    int start = s[t] - v0;   // exclusive
    bucketStart[t] = start;
    cursor[t] = start;
}

// ---------------------------------------------------------------- placement: bin edges by dst bucket
__global__ __launch_bounds__(256) void k_place(const int* __restrict__ src,
                                               const int* __restrict__ dst,
                                               int* __restrict__ cursor,
                                               int* __restrict__ ebuf, int E) {
    __shared__ int hist[MAXB];
    __shared__ int lbase[MAXB];
    __shared__ int lcur[MAXB];
    int t = threadIdx.x;
    int base = blockIdx.x * PCHUNK;
    for (int i = t; i < MAXB; i += 256) { hist[i] = 0; lcur[i] = 0; }
    __syncthreads();
    // pass 1: histogram this chunk
    for (int i = t; i < PCHUNK; i += 256) {
        int e = base + i;
        if (e < E) atomicAdd(&hist[dst[e] >> 7], 1);
    }
    __syncthreads();
    // reserve a contiguous slice per bucket
    for (int b = t; b < MAXB; b += 256)
        lbase[b] = hist[b] ? atomicAdd(&cursor[b], hist[b]) : 0;
    __syncthreads();
    // pass 2: scatter packed edges into reserved slices
    for (int i = t; i < PCHUNK; i += 256) {
        int e = base + i;
        if (e < E) {
            int s = src[e], d = dst[e];
            int b = d >> 7;
            int pos = lbase[b] + atomicAdd(&lcur[b], 1);
            ebuf[pos] = (s << 7) | (d & 127);
        }
    }
}

// ---------------------------------------------------------------- per-bucket degree (no global atomics)
__global__ __launch_bounds__(256) void k_bucket_deg(const int* __restrict__ bucketStart,
                                                    const int* __restrict__ bucketCount,
                                                    const int* __restrict__ ebuf,
                                                    int* __restrict__ deg, int N) {
    __shared__ int h[BN];
    int t = threadIdx.x, b = blockIdx.x;
    int start = bucketStart[b], cnt = bucketCount[b];
    for (int i = t; i < BN; i += 256) h[i] = 0;
    __syncthreads();
    for (int k = t; k < cnt; k += 256)
        atomicAdd(&h[ebuf[start + k] & 127], 1);
    __syncthreads();
    for (int i = t; i < BN; i += 256) {
        int node = b * BN + i;
        if (node < N) deg[node] = h[i];
    }
}

// ---------------------------------------------------------------- gemm1: g = (x @ W0) * dinv
__global__ __launch_bounds__(256) void k_gemm1(const float* __restrict__ x,
                                               const float* __restrict__ W0,
                                               const int* __restrict__ deg,
                                               float* __restrict__ g, int N) {
    int lane = threadIdx.x & 63;
    int q = lane >> 4;   // quarter of K
    int c = lane & 15;   // output channel
    float w[64];
#pragma unroll
    for (int t = 0; t < 64; ++t) w[t] = W0[(q * 64 + t) * CH + c];

    int wave  = (blockIdx.x * blockDim.x + threadIdx.x) >> 6;
    int nwave = (gridDim.x * blockDim.x) >> 6;
    for (int row = wave; row < N; row += nwave) {
        const float4* xp = (const float4*)(x + row * F_IN + q * 64);
        float acc = 0.f;
#pragma unroll
        for (int t = 0; t < 16; ++t) {
            float4 v = xp[t];
            acc += v.x * w[4*t] + v.y * w[4*t+1] + v.z * w[4*t+2] + v.w * w[4*t+3];
        }
        acc += __shfl_xor(acc, 16);
        acc += __shfl_xor(acc, 32);
        if (q == 0) {
            float dinv = rsqrtf((float)(deg[row] + 1));
            g[row * CH + c] = acc * dinv;
        }
    }
}

// ---------------------------------------------------------------- agg1: LDS-accumulate + relu + @W1 + scale
__global__ __launch_bounds__(256) void k_agg1(const int* __restrict__ bucketStart,
                                              const int* __restrict__ bucketCount,
                                              const int* __restrict__ ebuf,
                                              const int* __restrict__ deg,
                                              const float* __restrict__ g,
                                              const float* __restrict__ W1,
                                              float* __restrict__ g2, int N) {
    __shared__ float acc[BN * CH];   // 8 KB
    int t = threadIdx.x, b = blockIdx.x;
    int start = bucketStart[b], cnt = bucketCount[b];
    int base = b * BN;
    int c = t & 15;
    for (int i = t; i < BN * CH; i += 256) acc[i] = 0.f;
    __syncthreads();
    // 16 edges x 16 channels in flight per block-iteration
    for (int k = (t >> 4); k < cnt; k += 16) {
        int p = ebuf[start + k];          // broadcast within each 16-lane group
        int s = p >> 7, ld = p & 127;
        lds_fadd(&acc[ld * CH + c], g[s * CH + c]);
    }
    __syncthreads();
    // epilogue A: acc = relu(dinv * (acc + g_self))
    for (int i = t; i < BN * CH; i += 256) {
        int node = base + (i >> 4);
        if (node < N) {
            float dinv = rsqrtf((float)(deg[node] + 1));
            acc[i] = fmaxf(dinv * (acc[i] + g[node * CH + (i & 15)]), 0.f);
        }
    }
    __syncthreads();
    // epilogue B: g2 = (acc @ W1) * dinv   (8-padded channels)
    int j = t & 7;
    float w1[CH];
#pragma unroll
    for (int cc = 0; cc < CH; ++cc) w1[cc] = (j < NL) ? W1[cc * NL + j] : 0.f;
    for (int i = t; i < BN * 8; i += 256) {   // i&7 == j since 256 % 8 == 0
        int n = i >> 3, node = base + n;
        if (node < N) {
            float dinv = rsqrtf((float)(deg[node] + 1));
            float h2 = 0.f;
#pragma unroll
            for (int cc = 0; cc < CH; ++cc) h2 += acc[n * CH + cc] * w1[cc];
            g2[node * 8 + (i & 7)] = h2 * dinv;
        }
    }
}

// ---------------------------------------------------------------- agg2: LDS-accumulate + exp + 1
__global__ __launch_bounds__(256) void k_agg2(const int* __restrict__ bucketStart,
                                              const int* __restrict__ bucketCount,
                                              const int* __restrict__ ebuf,
                                              const int* __restrict__ deg,
                                              const float* __restrict__ g2,
                                              float* __restrict__ out, int N) {
    __shared__ float acc[BN * 8];    // 4 KB
    int t = threadIdx.x, b = blockIdx.x;
    int start = bucketStart[b], cnt = bucketCount[b];
    int base = b * BN;
    int j = t & 7;
    for (int i = t; i < BN * 8; i += 256) acc[i] = 0.f;
    __syncthreads();
    // 32 edges x 8 channels in flight per block-iteration
    for (int k = (t >> 3); k < cnt; k += 32) {
        int p = ebuf[start + k];
        int s = p >> 7, ld = p & 127;
        lds_fadd(&acc[ld * 8 + j], g2[s * 8 + j]);
    }
    __syncthreads();
    for (int i = t; i < BN * 8; i += 256) {
        int n = i >> 3, node = base + n, jj = i & 7;
        if (node < N && jj < NL) {
            float dinv = rsqrtf((float)(deg[node] + 1));
            out[node * NL + jj] = __expf(dinv * (acc[i] + g2[node * 8 + jj])) + 1.0f;
        }
    }
}

extern "C" void kernel_launch(void* const* d_in, const int* in_sizes, int n_in,
                              void* d_out, int out_size, void* d_ws, size_t ws_size,
                              hipStream_t stream) {
    const float* x  = (const float*)d_in[0];
    const float* W0 = (const float*)d_in[1];
    const float* W1 = (const float*)d_in[2];
    const int*   ei = (const int*)d_in[3];

    const int N = in_sizes[0] / F_IN;       // 100000
    const int E = in_sizes[3] / 2;          // 3200000
    const int* src = ei;
    const int* dst = ei + E;

    // ws layout (ints): bucketCount[MAXB] | bucketStart[MAXB] | cursor[MAXB] | deg[N] | ebuf[E] | g[N*16]f | g2[N*8]f
    int* bucketCount = (int*)d_ws;
    int* bucketStart = bucketCount + MAXB;
    int* cursor      = bucketStart + MAXB;
    int* deg         = cursor + MAXB;
    int* ebuf        = deg + N;
    float* g         = (float*)(ebuf + E);
    float* g2        = g + (size_t)N * CH;
    float* out       = (float*)d_out;

    const int nb = (N + BN - 1) / BN;       // 782

    hipMemsetAsync(bucketCount, 0, MAXB * sizeof(int), stream);

    k_count<<<512, 256, 0, stream>>>(dst, E, bucketCount);
    k_scan<<<1, MAXB, 0, stream>>>(bucketCount, bucketStart, cursor);
    k_place<<<(E + PCHUNK - 1) / PCHUNK, 256, 0, stream>>>(src, dst, cursor, ebuf, E);
    k_bucket_deg<<<nb, 256, 0, stream>>>(bucketStart, bucketCount, ebuf, deg, N);

    k_gemm1<<<2048, 256, 0, stream>>>(x, W0, deg, g, N);
    k_agg1<<<nb, 256, 0, stream>>>(bucketStart, bucketCount, ebuf, deg, g, W1, g2, N);
    k_agg2<<<nb, 256, 0, stream>>>(bucketStart, bucketCount, ebuf, deg, g2, out, N);
}

// Round 4
// 812.788 us; speedup vs baseline: 1.1112x; 1.1112x over previous
//
#include <hip/hip_runtime.h>
#include <math.h>

#define F_IN 256
#define CH   16
#define NL   7
#define BN   128            // nodes per bucket (localDst fits 7 bits)
#define MAXB 1024           // max buckets
#define PCHUNK 16384        // edges per placement block
#define CPB  4              // chunks per bucket for aggregation

__device__ __forceinline__ void lds_fadd(float* p, float v) {
    __hip_atomic_fetch_add(p, v, __ATOMIC_RELAXED, __HIP_MEMORY_SCOPE_WORKGROUP);
}

// ---------------------------------------------------------------- count edges per bucket
__global__ __launch_bounds__(256) void k_count(const int* __restrict__ dst, int E,
                                               int* __restrict__ bucketCount) {
    __shared__ int hist[MAXB];
    int t = threadIdx.x;
    for (int i = t; i < MAXB; i += 256) hist[i] = 0;
    __syncthreads();
    for (int e = blockIdx.x * 256 + t; e < E; e += gridDim.x * 256)
        atomicAdd(&hist[dst[e] >> 7], 1);
    __syncthreads();
    for (int b = t; b < MAXB; b += 256)
        if (hist[b]) atomicAdd(&bucketCount[b], hist[b]);
}

// ---------------------------------------------------------------- exclusive scan (1 block)
__global__ __launch_bounds__(MAXB) void k_scan(const int* __restrict__ bucketCount,
                                               int* __restrict__ bucketStart,
                                               int* __restrict__ cursor) {
    __shared__ int s[MAXB];
    int t = threadIdx.x;
    int v0 = bucketCount[t];
    s[t] = v0;
    __syncthreads();
    for (int d = 1; d < MAXB; d <<= 1) {
        int v = (t >= d) ? s[t - d] : 0;
        __syncthreads();
        s[t] += v;
        __syncthreads();
    }
    int start = s[t] - v0;   // exclusive
    bucketStart[t] = start;
    cursor[t] = start;
}

// ---------------------------------------------------------------- placement: bin edges by dst bucket
__global__ __launch_bounds__(256) void k_place(const int* __restrict__ src,
                                               const int* __restrict__ dst,
                                               int* __restrict__ cursor,
                                               int* __restrict__ ebuf, int E) {
    __shared__ int hist[MAXB];
    __shared__ int lbase[MAXB];
    __shared__ int lcur[MAXB];
    int t = threadIdx.x;
    int base = blockIdx.x * PCHUNK;
    for (int i = t; i < MAXB; i += 256) { hist[i] = 0; lcur[i] = 0; }
    __syncthreads();
    for (int i = t; i < PCHUNK; i += 256) {
        int e = base + i;
        if (e < E) atomicAdd(&hist[dst[e] >> 7], 1);
    }
    __syncthreads();
    for (int b = t; b < MAXB; b += 256)
        lbase[b] = hist[b] ? atomicAdd(&cursor[b], hist[b]) : 0;
    __syncthreads();
    for (int i = t; i < PCHUNK; i += 256) {
        int e = base + i;
        if (e < E) {
            int s = src[e], d = dst[e];
            int b = d >> 7;
            int pos = lbase[b] + atomicAdd(&lcur[b], 1);
            ebuf[pos] = (s << 7) | (d & 127);
        }
    }
}

// ---------------------------------------------------------------- per-bucket degree
__global__ __launch_bounds__(256) void k_bucket_deg(const int* __restrict__ bucketStart,
                                                    const int* __restrict__ bucketCount,
                                                    const int* __restrict__ ebuf,
                                                    int* __restrict__ deg, int N) {
    __shared__ int h[BN];
    int t = threadIdx.x, b = blockIdx.x;
    int start = bucketStart[b], cnt = bucketCount[b];
    for (int i = t; i < BN; i += 256) h[i] = 0;
    __syncthreads();
    for (int k = t; k < cnt; k += 256)
        atomicAdd(&h[ebuf[start + k] & 127], 1);
    __syncthreads();
    for (int i = t; i < BN; i += 256) {
        int node = b * BN + i;
        if (node < N) deg[node] = h[i];
    }
}

// ---------------------------------------------------------------- gemm1: g = (x @ W0) * dinv
__global__ __launch_bounds__(256) void k_gemm1(const float* __restrict__ x,
                                               const float* __restrict__ W0,
                                               const int* __restrict__ deg,
                                               float* __restrict__ g, int N) {
    int lane = threadIdx.x & 63;
    int q = lane >> 4;
    int c = lane & 15;
    float w[64];
#pragma unroll
    for (int t = 0; t < 64; ++t) w[t] = W0[(q * 64 + t) * CH + c];

    int wave  = (blockIdx.x * blockDim.x + threadIdx.x) >> 6;
    int nwave = (gridDim.x * blockDim.x) >> 6;
    for (int row = wave; row < N; row += nwave) {
        const float4* xp = (const float4*)(x + row * F_IN + q * 64);
        float acc = 0.f;
#pragma unroll
        for (int t = 0; t < 16; ++t) {
            float4 v = xp[t];
            acc += v.x * w[4*t] + v.y * w[4*t+1] + v.z * w[4*t+2] + v.w * w[4*t+3];
        }
        acc += __shfl_xor(acc, 16);
        acc += __shfl_xor(acc, 32);
        if (q == 0) {
            float dinv = rsqrtf((float)(deg[row] + 1));
            g[row * CH + c] = acc * dinv;
        }
    }
}

// ---------------------------------------------------------------- agg1: chunked LDS accumulate -> global atomic flush
__global__ __launch_bounds__(256) void k_agg1(const int* __restrict__ bucketStart,
                                              const int* __restrict__ bucketCount,
                                              const int* __restrict__ ebuf,
                                              const float* __restrict__ g,
                                              float* __restrict__ accA, int N) {
    __shared__ float acc[BN * CH];   // 8 KB
    int t = threadIdx.x;
    int b = blockIdx.x / CPB, cid = blockIdx.x % CPB;
    int start = bucketStart[b], cnt = bucketCount[b];
    int clen = (cnt + CPB - 1) / CPB;
    int kb = cid * clen, ke = min(cnt, kb + clen);
    if (kb >= ke) return;    // uniform per block: safe before barriers
    for (int i = t; i < BN * CH; i += 256) acc[i] = 0.f;
    __syncthreads();
    int c = t & 15, grp = t >> 4;    // 16 groups x 4-edge unroll = 64 edges/block-iter
    for (int k = kb + grp * 4; k < ke; k += 64) {
#pragma unroll
        for (int u = 0; u < 4; ++u) {
            int kk = k + u;
            if (kk < ke) {
                int p = ebuf[start + kk];
                int s = p >> 7, ld = p & 127;
                lds_fadd(&acc[ld * CH + c], g[s * CH + c]);
            }
        }
    }
    __syncthreads();
    float* dstp = accA + (size_t)b * BN * CH;   // contiguous 8 KB region
    for (int i = t; i < BN * CH; i += 256) {
        float v = acc[i];
        if (v != 0.f) unsafeAtomicAdd(&dstp[i], v);
    }
}

// ---------------------------------------------------------------- post1: g2 = relu(dinv*(accA+g)) @ W1 * dinv
__global__ __launch_bounds__(256) void k_post1(const float* __restrict__ g,
                                               const float* __restrict__ accA,
                                               const float* __restrict__ W1,
                                               const int* __restrict__ deg,
                                               float* __restrict__ g2, int N) {
    int j = threadIdx.x & 7;
    float w1[CH];
#pragma unroll
    for (int c = 0; c < CH; ++c) w1[c] = (j < NL) ? W1[c * NL + j] : 0.f;
    int row = (blockIdx.x * blockDim.x + threadIdx.x) >> 3;
    if (row >= N) return;
    float dinv = rsqrtf((float)(deg[row] + 1));
    const float4* gp = (const float4*)(g + row * CH);
    const float4* ap = (const float4*)(accA + row * CH);
    float h2 = 0.f;
#pragma unroll
    for (int t = 0; t < 4; ++t) {
        float4 gv = gp[t], av = ap[t];
        float h;
        h = fmaxf(dinv * (gv.x + av.x), 0.f); h2 += h * w1[4*t+0];
        h = fmaxf(dinv * (gv.y + av.y), 0.f); h2 += h * w1[4*t+1];
        h = fmaxf(dinv * (gv.z + av.z), 0.f); h2 += h * w1[4*t+2];
        h = fmaxf(dinv * (gv.w + av.w), 0.f); h2 += h * w1[4*t+3];
    }
    g2[row * 8 + j] = h2 * dinv;
}

// ---------------------------------------------------------------- agg2: chunked LDS accumulate -> global atomic flush
__global__ __launch_bounds__(256) void k_agg2(const int* __restrict__ bucketStart,
                                              const int* __restrict__ bucketCount,
                                              const int* __restrict__ ebuf,
                                              const float* __restrict__ g2,
                                              float* __restrict__ accB, int N) {
    __shared__ float acc[BN * 8];    // 4 KB
    int t = threadIdx.x;
    int b = blockIdx.x / CPB, cid = blockIdx.x % CPB;
    int start = bucketStart[b], cnt = bucketCount[b];
    int clen = (cnt + CPB - 1) / CPB;
    int kb = cid * clen, ke = min(cnt, kb + clen);
    if (kb >= ke) return;
    for (int i = t; i < BN * 8; i += 256) acc[i] = 0.f;
    __syncthreads();
    int j = t & 7, grp = t >> 3;     // 32 groups x 4-edge unroll = 128 edges/block-iter
    for (int k = kb + grp * 4; k < ke; k += 128) {
#pragma unroll
        for (int u = 0; u < 4; ++u) {
            int kk = k + u;
            if (kk < ke) {
                int p = ebuf[start + kk];
                int s = p >> 7, ld = p & 127;
                lds_fadd(&acc[ld * 8 + j], g2[s * 8 + j]);
            }
        }
    }
    __syncthreads();
    float* dstp = accB + (size_t)b * BN * 8;
    for (int i = t; i < BN * 8; i += 256) {
        float v = acc[i];
        if (v != 0.f) unsafeAtomicAdd(&dstp[i], v);
    }
}

// ---------------------------------------------------------------- finalize: out = exp(dinv*(accB+g2)) + 1
__global__ void k_final(const float* __restrict__ g2, const float* __restrict__ accB,
                        const int* __restrict__ deg, float* __restrict__ out, int N) {
    int tid = blockIdx.x * blockDim.x + threadIdx.x;
    int row = tid >> 3, j = tid & 7;
    if (row >= N || j >= NL) return;
    float dinv = rsqrtf((float)(deg[row] + 1));
    out[row * NL + j] = __expf(dinv * (g2[row * 8 + j] + accB[row * 8 + j])) + 1.0f;
}

extern "C" void kernel_launch(void* const* d_in, const int* in_sizes, int n_in,
                              void* d_out, int out_size, void* d_ws, size_t ws_size,
                              hipStream_t stream) {
    const float* x  = (const float*)d_in[0];
    const float* W0 = (const float*)d_in[1];
    const float* W1 = (const float*)d_in[2];
    const int*   ei = (const int*)d_in[3];

    const int N = in_sizes[0] / F_IN;       // 100000
    const int E = in_sizes[3] / 2;          // 3200000
    const int* src = ei;
    const int* dst = ei + E;

    // ws: accA[N*16]f | accB[N*8]f | bucketCount | bucketStart | cursor | deg[N] | ebuf[E] | g[N*16]f | g2[N*8]f
    float* accA       = (float*)d_ws;
    float* accB       = accA + (size_t)N * CH;
    int*   bucketCount= (int*)(accB + (size_t)N * 8);
    int*   bucketStart= bucketCount + MAXB;
    int*   cursor     = bucketStart + MAXB;
    int*   deg        = cursor + MAXB;
    int*   ebuf       = deg + N;
    float* g          = (float*)(ebuf + E);
    float* g2         = g + (size_t)N * CH;
    float* out        = (float*)d_out;

    const int nb = (N + BN - 1) / BN;       // 782

    // zero accA+accB (contiguous) and bucketCount
    hipMemsetAsync(accA, 0, (size_t)N * (CH + 8) * sizeof(float), stream);
    hipMemsetAsync(bucketCount, 0, MAXB * sizeof(int), stream);

    k_count<<<512, 256, 0, stream>>>(dst, E, bucketCount);
    k_scan<<<1, MAXB, 0, stream>>>(bucketCount, bucketStart, cursor);
    k_place<<<(E + PCHUNK - 1) / PCHUNK, 256, 0, stream>>>(src, dst, cursor, ebuf, E);
    k_bucket_deg<<<nb, 256, 0, stream>>>(bucketStart, bucketCount, ebuf, deg, N);

    k_gemm1<<<2048, 256, 0, stream>>>(x, W0, deg, g, N);
    k_agg1<<<nb * CPB, 256, 0, stream>>>(bucketStart, bucketCount, ebuf, g, accA, N);
    k_post1<<<(N * 8 + 255) / 256, 256, 0, stream>>>(g, accA, W1, deg, g2, N);
    k_agg2<<<nb * CPB, 256, 0, stream>>>(bucketStart, bucketCount, ebuf, g2, accB, N);
    k_final<<<(N * 8 + 255) / 256, 256, 0, stream>>>(g2, accB, deg, out, N);
}